// Round 13
// baseline (183.737 us; speedup 1.0000x reference)
//
#include <hip/hip_runtime.h>

// ExpanderLinearLayer: out[M,N] = input[M,K] @ (W[N,K]*mask[N,K])^T
// M=16384, N=2048, K=2048, fp32 in/out.
// bf16 conversion + 256x256 MFMA GEMM (16x16x32). 64 phases of
// {STG(t+3); VMCNT(8); barA; 12 asm ds_read_b128 (slot t+1); lgkmcnt(12)
//  [completes t-1's reads, leaves ours in flight]; 32 MFMA; barB}.
// R12 issued the reads mid-cluster -> only ~620 cyc shadow for a 1152-cyc
// drain. Now reads issue at cluster TOP and the consuming wait is COUNTED,
// giving a full cluster (1242 cyc) + barrier gap of drain shadow.

#define MDIM 16384
#define NDIM 2048
#define KDIM 2048

#define BM 256
#define BN 256
#define GRID_X ((MDIM / BM) * (NDIM / BN))  // 64*8 = 512

using f32x4   = __attribute__((ext_vector_type(4))) float;
using bf16x8  = __attribute__((ext_vector_type(8))) __bf16;
using ushort8 = __attribute__((ext_vector_type(8))) unsigned short;

typedef __attribute__((address_space(3))) const unsigned short* lds_cptr_t;

__device__ __forceinline__ unsigned short f2bf(float f) {
  unsigned int u = __builtin_bit_cast(unsigned int, f);
  u = u + 0x7FFFu + ((u >> 16) & 1u);  // RNE
  return (unsigned short)(u >> 16);
}

// ---------------- conversion kernels ----------------

__global__ void convert_input_kernel(const float* __restrict__ in,
                                     unsigned short* __restrict__ out) {
  size_t base = ((size_t)blockIdx.x * blockDim.x + threadIdx.x) * 8;
  float4 a = *reinterpret_cast<const float4*>(in + base);
  float4 b = *reinterpret_cast<const float4*>(in + base + 4);
  ushort8 v;
  v[0] = f2bf(a.x); v[1] = f2bf(a.y); v[2] = f2bf(a.z); v[3] = f2bf(a.w);
  v[4] = f2bf(b.x); v[5] = f2bf(b.y); v[6] = f2bf(b.z); v[7] = f2bf(b.w);
  *reinterpret_cast<ushort8*>(out + base) = v;
}

__global__ void convert_weight_kernel(const float* __restrict__ w,
                                      const int* __restrict__ mk,
                                      unsigned short* __restrict__ out) {
  size_t base = ((size_t)blockIdx.x * blockDim.x + threadIdx.x) * 8;
  float4 a = *reinterpret_cast<const float4*>(w + base);
  float4 b = *reinterpret_cast<const float4*>(w + base + 4);
  int4 m0 = *reinterpret_cast<const int4*>(mk + base);
  int4 m1 = *reinterpret_cast<const int4*>(mk + base + 4);
  ushort8 v;
  v[0] = m0.x ? f2bf(a.x) : (unsigned short)0;
  v[1] = m0.y ? f2bf(a.y) : (unsigned short)0;
  v[2] = m0.z ? f2bf(a.z) : (unsigned short)0;
  v[3] = m0.w ? f2bf(a.w) : (unsigned short)0;
  v[4] = m1.x ? f2bf(b.x) : (unsigned short)0;
  v[5] = m1.y ? f2bf(b.y) : (unsigned short)0;
  v[6] = m1.z ? f2bf(b.z) : (unsigned short)0;
  v[7] = m1.w ? f2bf(b.w) : (unsigned short)0;
  *reinterpret_cast<ushort8*>(out + base) = v;
}

// ---------------- read-ahead asm GEMM (counted lgkm) ----------------

__device__ __forceinline__ f32x4 MF(bf16x8 a, bf16x8 b, f32x4 c) {
  return __builtin_amdgcn_mfma_f32_16x16x32_bf16(a, b, c, 0, 0, 0);
}
#define VMCNT(n) asm volatile("s_waitcnt vmcnt(" #n ")" ::: "memory")
#define LGKM(n)  asm volatile("s_waitcnt lgkmcnt(" #n ")" ::: "memory")
#define DSR(dst, p, off)                                                        \
  asm volatile("ds_read_b128 %0, %1 offset:%2" : "=v"(dst) : "v"(p), "i"(off))

// LDS: per operand 4 slots [buf(2)][khalf(2)] of 256 rows x 32 k bf16
// (16 KiB each); slot (b,kh) byte base = (b*2+kh)*16384 (offset immediate).
// Swizzle (verified conflict-free R3): 16-B chunk' = chunk ^ ((row>>1)&3),
// on pre-swizzled global source (gload_lds dest linear) + ds_read addrs.
// Schedule (R6/R11/R12-verified): slot staged at t-3, retired by VMCNT(8)
// at t-1, published by t-1's barA; READ at top of t-1's cluster; completed
// by t's counted lgkmcnt(12); consumed by t's MFMA cluster.
__global__ __launch_bounds__(512, 2) void gemm_ra2(
    const unsigned short* __restrict__ Abf,
    const unsigned short* __restrict__ Bbf,
    float* __restrict__ C) {
  __shared__ __attribute__((aligned(16))) unsigned short Asl[4 * 8192];
  __shared__ __attribute__((aligned(16))) unsigned short Bsl[4 * 8192];

  // bijective XCD swizzle (512 % 8 == 0) -- R3's proven map (FETCH ~98 MB)
  int bid = blockIdx.x;
  int wgs = (bid & 7) * (GRID_X / 8) + (bid >> 3);
  int tm = wgs >> 3;  // NDIM/BN == 8
  int tn = wgs & 7;
  int row0 = tm * BM, col0 = tn * BN;

  int t = threadIdx.x;
  int lane = t & 63, wid = t >> 6;
  int wr = wid >> 2, wc = wid & 3;       // 2 x 4 wave grid, wave tile 128x64
  int fr = lane & 15, fq = lane >> 4;

  // staging: thread covers chunks p0 and p0+64 (rows r0, r0+16; swizzle key
  // (r>>1)&3 invariant under +16 rows -> same inverse-swizzled k-chunk).
  int p0 = (wid * 2) * 64 + lane;
  int r0 = p0 >> 2, kc0 = ((p0 & 3) ^ ((r0 >> 1) & 3)) * 8;
  size_t offA0 = (size_t)(row0 + r0) * KDIM + kc0;
  size_t offB0 = (size_t)(col0 + r0) * KDIM + kc0;
  int ldsw0 = (wid * 2) * 512;  // elements; wave-uniform

  // frag ds_read base addrs (AS3); per-slot/per-frag via offset: immediate
  int kxor = (fq ^ ((fr >> 1) & 3)) * 8;
  int aoff = (wr * 128 + fr) * 32 + kxor;   // elements
  int boff = (wc * 64 + fr) * 32 + kxor;
  lds_cptr_t aA = ((lds_cptr_t)Asl) + aoff;
  lds_cptr_t aB = ((lds_cptr_t)Bsl) + boff;

  f32x4 acc[8][4];
#pragma unroll
  for (int m = 0; m < 8; ++m)
#pragma unroll
    for (int n = 0; n < 4; ++n) acc[m][n] = f32x4{0.f, 0.f, 0.f, 0.f};

  bf16x8 aP[8], bP[4], aQ[8], bQ[4];  // double-buffered frag registers

#define SLOT_A(b, kh) (Asl + ((b) * 2 + (kh)) * 8192)
#define SLOT_B(b, kh) (Bsl + ((b) * 2 + (kh)) * 8192)

#define STG(slot, base, o0, ke) do {                                            \
  __builtin_amdgcn_global_load_lds(                                             \
      (const __attribute__((address_space(1))) void*)((base) + (o0) + (ke)),    \
      (__attribute__((address_space(3))) void*)((slot) + ldsw0), 16, 0, 0);     \
  __builtin_amdgcn_global_load_lds(                                             \
      (const __attribute__((address_space(1))) void*)((base) + (o0) + 32768 +   \
                                                      (ke)),                    \
      (__attribute__((address_space(3))) void*)((slot) + ldsw0 + 512), 16, 0,   \
      0);                                                                       \
} while (0)

// 12 asm reads of slot (b,kh) into (AD, BD)
#define RD12(b, kh, AD, BD) do {                                                \
  DSR(AD[0], aA, ((b) * 2 + (kh)) * 16384 + 0 * 1024);                          \
  DSR(AD[1], aA, ((b) * 2 + (kh)) * 16384 + 1 * 1024);                          \
  DSR(AD[2], aA, ((b) * 2 + (kh)) * 16384 + 2 * 1024);                          \
  DSR(AD[3], aA, ((b) * 2 + (kh)) * 16384 + 3 * 1024);                          \
  DSR(AD[4], aA, ((b) * 2 + (kh)) * 16384 + 4 * 1024);                          \
  DSR(AD[5], aA, ((b) * 2 + (kh)) * 16384 + 5 * 1024);                          \
  DSR(AD[6], aA, ((b) * 2 + (kh)) * 16384 + 6 * 1024);                          \
  DSR(AD[7], aA, ((b) * 2 + (kh)) * 16384 + 7 * 1024);                          \
  DSR(BD[0], aB, ((b) * 2 + (kh)) * 16384 + 0 * 1024);                          \
  DSR(BD[1], aB, ((b) * 2 + (kh)) * 16384 + 1 * 1024);                          \
  DSR(BD[2], aB, ((b) * 2 + (kh)) * 16384 + 2 * 1024);                          \
  DSR(BD[3], aB, ((b) * 2 + (kh)) * 16384 + 3 * 1024);                          \
} while (0)

// phase t: STG(t+3); VMCNT(8) retires slot t+1; barA publishes it; 12 asm
// reads of slot t+1 (into the idle frag buffer); lgkmcnt(12) completes the
// 12 reads issued at t-1 (DS ops complete in order; only DS in flight) while
// ours stay outstanding across the whole cluster; 32 reg-only MFMA; barB.
#define PHASE(rb, rkh, AC, BC, AD, BD, STAGES, WAITS) do {                      \
  STAGES;                                                                       \
  WAITS;                                                                        \
  __builtin_amdgcn_s_barrier();                                                 \
  RD12(rb, rkh, AD, BD);                                                        \
  LGKM(12);                                                                     \
  __builtin_amdgcn_sched_barrier(0);                                            \
  __builtin_amdgcn_s_setprio(1);                                                \
  _Pragma("unroll")                                                             \
  for (int _m = 0; _m < 8; ++_m)                                                \
    _Pragma("unroll")                                                           \
    for (int _n = 0; _n < 4; ++_n)                                              \
      acc[_m][_n] = MF(AC[_m], BC[_n], acc[_m][_n]);                            \
  __builtin_amdgcn_s_setprio(0);                                                \
  __builtin_amdgcn_s_barrier();                                                 \
} while (0)

  // prologue: stage slots (0,0),(0,1),(1,0) = 12 vmem ops; retire slot (0,0)
  // (VMCNT(8)), publish, then asm-read its frags into P (completed by phase
  // 0's counted lgkmcnt(12)).
  STG(SLOT_A(0, 0), Abf, offA0, 0);
  STG(SLOT_B(0, 0), Bbf, offB0, 0);
  STG(SLOT_A(0, 1), Abf, offA0, 32);
  STG(SLOT_B(0, 1), Bbf, offB0, 32);
  STG(SLOT_A(1, 0), Abf, offA0, 64);
  STG(SLOT_B(1, 0), Bbf, offB0, 64);
  VMCNT(8);
  __builtin_amdgcn_s_barrier();
  RD12(0, 0, aP, bP);

  // main loop: phases t=0..59. Consume slot t (P/Q regs), read-ahead t+1.
  for (int i = 0; i < 15; ++i) {
    int kb = i * 128;
    PHASE(0, 1, aP, bP, aQ, bQ, { STG(SLOT_A(1, 1), Abf, offA0, kb + 96);
                                  STG(SLOT_B(1, 1), Bbf, offB0, kb + 96); },
          VMCNT(8));
    PHASE(1, 0, aQ, bQ, aP, bP, { STG(SLOT_A(0, 0), Abf, offA0, kb + 128);
                                  STG(SLOT_B(0, 0), Bbf, offB0, kb + 128); },
          VMCNT(8));
    PHASE(1, 1, aP, bP, aQ, bQ, { STG(SLOT_A(0, 1), Abf, offA0, kb + 160);
                                  STG(SLOT_B(0, 1), Bbf, offB0, kb + 160); },
          VMCNT(8));
    PHASE(0, 0, aQ, bQ, aP, bP, { STG(SLOT_A(1, 0), Abf, offA0, kb + 192);
                                  STG(SLOT_B(1, 0), Bbf, offB0, kb + 192); },
          VMCNT(8));
  }
  // tail: t=60..62 (drain 8 -> 4 -> 0), then bare cluster at t=63.
  PHASE(0, 1, aP, bP, aQ, bQ, { STG(SLOT_A(1, 1), Abf, offA0, 2016);
                                STG(SLOT_B(1, 1), Bbf, offB0, 2016); },
        VMCNT(8));
  PHASE(1, 0, aQ, bQ, aP, bP, , VMCNT(4));
  PHASE(1, 1, aP, bP, aQ, bQ, , VMCNT(0));
  {
    LGKM(0);
    __builtin_amdgcn_sched_barrier(0);
#pragma unroll
    for (int m = 0; m < 8; ++m)
#pragma unroll
      for (int n = 0; n < 4; ++n)
        acc[m][n] = MF(aQ[m], bQ[n], acc[m][n]);
  }

  // epilogue: C/D layout (verified m89) col=lane&15, row=(lane>>4)*4+reg
  size_t crow = (size_t)(row0 + wr * 128 + fq * 4);
  int ccol = col0 + wc * 64 + fr;
#pragma unroll
  for (int m = 0; m < 8; ++m)
#pragma unroll
    for (int n = 0; n < 4; ++n) {
      float* cp = C + (crow + m * 16) * NDIM + ccol + n * 16;
#pragma unroll
      for (int e = 0; e < 4; ++e) cp[(size_t)e * NDIM] = acc[m][n][e];
    }
#undef PHASE
#undef RD12
#undef STG
#undef SLOT_A
#undef SLOT_B
}

// ---------------- fallback (fused conversion, 128^2 m97-structure) ----------

__global__ __launch_bounds__(256) void gemm_fused_fallback(
    const float* __restrict__ Afp,
    const float* __restrict__ Wfp,
    const int* __restrict__ Mk,
    float* __restrict__ C) {
  __shared__ unsigned short As[128 * 32];
  __shared__ unsigned short Bs[128 * 32];
  int bid = blockIdx.x;
  int nwg = (MDIM / 128) * (NDIM / 128);
  int wg = (bid & 7) * (nwg / 8) + (bid >> 3);
  int tm = wg >> 4, tn = wg & 15;
  int row0 = tm * 128, col0 = tn * 128;
  int t = threadIdx.x;
  int lane = t & 63, wv = t >> 6;
  int wr = wv >> 1, wc = wv & 1;
  int fr = lane & 15, fq = lane >> 4;
  f32x4 acc[4][4];
#pragma unroll
  for (int i = 0; i < 4; ++i)
#pragma unroll
    for (int j = 0; j < 4; ++j) acc[i][j] = f32x4{0.f, 0.f, 0.f, 0.f};
  for (int kt = 0; kt < KDIM; kt += 32) {
#pragma unroll
    for (int j = 0; j < 2; ++j) {
      int c = j * 256 + t;
      int r = c >> 2;
      int ko = (c & 3) * 8;
      const float* ga = Afp + (size_t)(row0 + r) * KDIM + kt + ko;
      float4 a0 = *reinterpret_cast<const float4*>(ga);
      float4 a1 = *reinterpret_cast<const float4*>(ga + 4);
      ushort8 va;
      va[0] = f2bf(a0.x); va[1] = f2bf(a0.y); va[2] = f2bf(a0.z); va[3] = f2bf(a0.w);
      va[4] = f2bf(a1.x); va[5] = f2bf(a1.y); va[6] = f2bf(a1.z); va[7] = f2bf(a1.w);
      *reinterpret_cast<ushort8*>(As + (size_t)c * 8) = va;
      const float* gw = Wfp + (size_t)(col0 + r) * KDIM + kt + ko;
      const int* gm = Mk + (size_t)(col0 + r) * KDIM + kt + ko;
      float4 w0 = *reinterpret_cast<const float4*>(gw);
      float4 w1 = *reinterpret_cast<const float4*>(gw + 4);
      int4 m0 = *reinterpret_cast<const int4*>(gm);
      int4 m1 = *reinterpret_cast<const int4*>(gm + 4);
      ushort8 vb;
      vb[0] = m0.x ? f2bf(w0.x) : (unsigned short)0;
      vb[1] = m0.y ? f2bf(w0.y) : (unsigned short)0;
      vb[2] = m0.z ? f2bf(w0.z) : (unsigned short)0;
      vb[3] = m0.w ? f2bf(w0.w) : (unsigned short)0;
      vb[4] = m1.x ? f2bf(w1.x) : (unsigned short)0;
      vb[5] = m1.y ? f2bf(w1.y) : (unsigned short)0;
      vb[6] = m1.z ? f2bf(w1.z) : (unsigned short)0;
      vb[7] = m1.w ? f2bf(w1.w) : (unsigned short)0;
      *reinterpret_cast<ushort8*>(Bs + (size_t)c * 8) = vb;
    }
    __syncthreads();
    bf16x8 af[4], bfr[4];
#pragma unroll
    for (int m2 = 0; m2 < 4; ++m2)
      af[m2] = *reinterpret_cast<const bf16x8*>(As + (wr * 64 + m2 * 16 + fr) * 32 + fq * 8);
#pragma unroll
    for (int n2 = 0; n2 < 4; ++n2)
      bfr[n2] = *reinterpret_cast<const bf16x8*>(Bs + (wc * 64 + n2 * 16 + fr) * 32 + fq * 8);
#pragma unroll
    for (int m2 = 0; m2 < 4; ++m2)
#pragma unroll
      for (int n2 = 0; n2 < 4; ++n2)
        acc[m2][n2] = MF(af[m2], bfr[n2], acc[m2][n2]);
    __syncthreads();
  }
#pragma unroll
  for (int m2 = 0; m2 < 4; ++m2)
#pragma unroll
    for (int n2 = 0; n2 < 4; ++n2) {
      size_t r0 = (size_t)(row0 + wr * 64 + m2 * 16 + fq * 4);
      size_t c0 = (size_t)(col0 + wc * 64 + n2 * 16 + fr);
#pragma unroll
      for (int i = 0; i < 4; ++i) C[(r0 + i) * NDIM + c0] = acc[m2][n2][i];
    }
}

// ---------------- launch ----------------

extern "C" void kernel_launch(void* const* d_in, const int* in_sizes, int n_in,
                              void* d_out, int out_size, void* d_ws, size_t ws_size,
                              hipStream_t stream) {
  const float* input  = (const float*)d_in[0];
  const float* weight = (const float*)d_in[1];
  const int*   mask   = (const int*)d_in[2];
  float* out = (float*)d_out;

  const size_t needA = (size_t)MDIM * KDIM * sizeof(unsigned short);
  const size_t needB = (size_t)NDIM * KDIM * sizeof(unsigned short);

  if (ws_size >= needA + needB) {
    unsigned short* Abf = (unsigned short*)d_ws;
    unsigned short* Bbf = (unsigned short*)((char*)d_ws + needA);
    convert_input_kernel<<<(MDIM * (size_t)KDIM / 8) / 256, 256, 0, stream>>>(input, Abf);
    convert_weight_kernel<<<(NDIM * (size_t)KDIM / 8) / 256, 256, 0, stream>>>(weight, mask, Bbf);
    gemm_ra2<<<GRID_X, 512, 0, stream>>>(Abf, Bbf, out);
  } else {
    int nwg = (MDIM / 128) * (NDIM / 128);
    gemm_fused_fallback<<<nwg, 256, 0, stream>>>(input, weight, mask, out);
  }
}

// Round 14
// 167.406 us; speedup vs baseline: 1.0976x; 1.0976x over previous
//
#include <hip/hip_runtime.h>

// ExpanderLinearLayer: out[M,N] = input[M,K] @ (W[N,K]*mask[N,K])^T
// M=16384, N=2048, K=2048, fp32 in/out.
// bf16 conversion + 256x256 MFMA GEMM (16x16x32). 64 phases of
// {STG(t+3); VMCNT(8); LGKM(0); barA; 16 MFMA; 12 asm ds_read (slot t+1);
//  16 MFMA}  -- R12's verified pipeline with barB REMOVED: moving lgkmcnt(0)
// before barA makes all reads of slot t provably complete at barA(t), so the
// t+1 STG overwrite (issued only after barA(t)) needs no second barrier.
// Halves barrier count; clusters slide across phase edges (smoother LDS).

#define MDIM 16384
#define NDIM 2048
#define KDIM 2048

#define BM 256
#define BN 256
#define GRID_X ((MDIM / BM) * (NDIM / BN))  // 64*8 = 512

using f32x4   = __attribute__((ext_vector_type(4))) float;
using bf16x8  = __attribute__((ext_vector_type(8))) __bf16;
using ushort8 = __attribute__((ext_vector_type(8))) unsigned short;

typedef __attribute__((address_space(3))) const unsigned short* lds_cptr_t;

__device__ __forceinline__ unsigned short f2bf(float f) {
  unsigned int u = __builtin_bit_cast(unsigned int, f);
  u = u + 0x7FFFu + ((u >> 16) & 1u);  // RNE
  return (unsigned short)(u >> 16);
}

// ---------------- conversion kernels ----------------

__global__ void convert_input_kernel(const float* __restrict__ in,
                                     unsigned short* __restrict__ out) {
  size_t base = ((size_t)blockIdx.x * blockDim.x + threadIdx.x) * 8;
  float4 a = *reinterpret_cast<const float4*>(in + base);
  float4 b = *reinterpret_cast<const float4*>(in + base + 4);
  ushort8 v;
  v[0] = f2bf(a.x); v[1] = f2bf(a.y); v[2] = f2bf(a.z); v[3] = f2bf(a.w);
  v[4] = f2bf(b.x); v[5] = f2bf(b.y); v[6] = f2bf(b.z); v[7] = f2bf(b.w);
  *reinterpret_cast<ushort8*>(out + base) = v;
}

__global__ void convert_weight_kernel(const float* __restrict__ w,
                                      const int* __restrict__ mk,
                                      unsigned short* __restrict__ out) {
  size_t base = ((size_t)blockIdx.x * blockDim.x + threadIdx.x) * 8;
  float4 a = *reinterpret_cast<const float4*>(w + base);
  float4 b = *reinterpret_cast<const float4*>(w + base + 4);
  int4 m0 = *reinterpret_cast<const int4*>(mk + base);
  int4 m1 = *reinterpret_cast<const int4*>(mk + base + 4);
  ushort8 v;
  v[0] = m0.x ? f2bf(a.x) : (unsigned short)0;
  v[1] = m0.y ? f2bf(a.y) : (unsigned short)0;
  v[2] = m0.z ? f2bf(a.z) : (unsigned short)0;
  v[3] = m0.w ? f2bf(a.w) : (unsigned short)0;
  v[4] = m1.x ? f2bf(b.x) : (unsigned short)0;
  v[5] = m1.y ? f2bf(b.y) : (unsigned short)0;
  v[6] = m1.z ? f2bf(b.z) : (unsigned short)0;
  v[7] = m1.w ? f2bf(b.w) : (unsigned short)0;
  *reinterpret_cast<ushort8*>(out + base) = v;
}

// ---------------- single-barrier read-ahead asm GEMM ----------------

__device__ __forceinline__ f32x4 MF(bf16x8 a, bf16x8 b, f32x4 c) {
  return __builtin_amdgcn_mfma_f32_16x16x32_bf16(a, b, c, 0, 0, 0);
}
#define VMCNT(n) asm volatile("s_waitcnt vmcnt(" #n ")" ::: "memory")
#define LGKM(n)  asm volatile("s_waitcnt lgkmcnt(" #n ")" ::: "memory")
#define DSR(dst, p, off)                                                        \
  asm volatile("ds_read_b128 %0, %1 offset:%2" : "=v"(dst) : "v"(p), "i"(off))

// LDS: per operand 4 slots [buf(2)][khalf(2)] of 256 rows x 32 k bf16
// (16 KiB each); slot (b,kh) byte base = (b*2+kh)*16384 (offset immediate).
// Swizzle (verified conflict-free R3): 16-B chunk' = chunk ^ ((row>>1)&3),
// on pre-swizzled global source (gload_lds dest linear) + ds_read addrs.
// Hazards (single barrier, proven): RAW -- slot t+1 retired by VMCNT(8)@t,
// published by barA(t), read mid-cluster t. WAR -- reads of slot t complete
// at LGKM(0)@t BEFORE barA(t); overwrite STG issues at t+1 after barA(t).
__global__ __launch_bounds__(512, 2) void gemm_1b(
    const unsigned short* __restrict__ Abf,
    const unsigned short* __restrict__ Bbf,
    float* __restrict__ C) {
  __shared__ __attribute__((aligned(16))) unsigned short Asl[4 * 8192];
  __shared__ __attribute__((aligned(16))) unsigned short Bsl[4 * 8192];

  // bijective XCD swizzle (512 % 8 == 0) -- R3's proven map (FETCH ~98 MB)
  int bid = blockIdx.x;
  int wgs = (bid & 7) * (GRID_X / 8) + (bid >> 3);
  int tm = wgs >> 3;  // NDIM/BN == 8
  int tn = wgs & 7;
  int row0 = tm * BM, col0 = tn * BN;

  int t = threadIdx.x;
  int lane = t & 63, wid = t >> 6;
  int wr = wid >> 2, wc = wid & 3;       // 2 x 4 wave grid, wave tile 128x64
  int fr = lane & 15, fq = lane >> 4;

  // staging: thread covers chunks p0 and p0+64 (rows r0, r0+16; swizzle key
  // (r>>1)&3 invariant under +16 rows -> same inverse-swizzled k-chunk).
  int p0 = (wid * 2) * 64 + lane;
  int r0 = p0 >> 2, kc0 = ((p0 & 3) ^ ((r0 >> 1) & 3)) * 8;
  size_t offA0 = (size_t)(row0 + r0) * KDIM + kc0;
  size_t offB0 = (size_t)(col0 + r0) * KDIM + kc0;
  int ldsw0 = (wid * 2) * 512;  // elements; wave-uniform

  // frag ds_read base addrs (AS3); per-slot/per-frag via offset: immediate
  int kxor = (fq ^ ((fr >> 1) & 3)) * 8;
  int aoff = (wr * 128 + fr) * 32 + kxor;   // elements
  int boff = (wc * 64 + fr) * 32 + kxor;
  lds_cptr_t aA = ((lds_cptr_t)Asl) + aoff;
  lds_cptr_t aB = ((lds_cptr_t)Bsl) + boff;

  f32x4 acc[8][4];
#pragma unroll
  for (int m = 0; m < 8; ++m)
#pragma unroll
    for (int n = 0; n < 4; ++n) acc[m][n] = f32x4{0.f, 0.f, 0.f, 0.f};

  bf16x8 aP[8], bP[4], aQ[8], bQ[4];  // double-buffered frag registers

#define SLOT_A(b, kh) (Asl + ((b) * 2 + (kh)) * 8192)
#define SLOT_B(b, kh) (Bsl + ((b) * 2 + (kh)) * 8192)

#define STG(slot, base, o0, ke) do {                                            \
  __builtin_amdgcn_global_load_lds(                                             \
      (const __attribute__((address_space(1))) void*)((base) + (o0) + (ke)),    \
      (__attribute__((address_space(3))) void*)((slot) + ldsw0), 16, 0, 0);     \
  __builtin_amdgcn_global_load_lds(                                             \
      (const __attribute__((address_space(1))) void*)((base) + (o0) + 32768 +   \
                                                      (ke)),                    \
      (__attribute__((address_space(3))) void*)((slot) + ldsw0 + 512), 16, 0,   \
      0);                                                                       \
} while (0)

// 12 asm reads of slot (b,kh) into (AD, BD)
#define RD12(b, kh, AD, BD) do {                                                \
  DSR(AD[0], aA, ((b) * 2 + (kh)) * 16384 + 0 * 1024);                          \
  DSR(AD[1], aA, ((b) * 2 + (kh)) * 16384 + 1 * 1024);                          \
  DSR(AD[2], aA, ((b) * 2 + (kh)) * 16384 + 2 * 1024);                          \
  DSR(AD[3], aA, ((b) * 2 + (kh)) * 16384 + 3 * 1024);                          \
  DSR(AD[4], aA, ((b) * 2 + (kh)) * 16384 + 4 * 1024);                          \
  DSR(AD[5], aA, ((b) * 2 + (kh)) * 16384 + 5 * 1024);                          \
  DSR(AD[6], aA, ((b) * 2 + (kh)) * 16384 + 6 * 1024);                          \
  DSR(AD[7], aA, ((b) * 2 + (kh)) * 16384 + 7 * 1024);                          \
  DSR(BD[0], aB, ((b) * 2 + (kh)) * 16384 + 0 * 1024);                          \
  DSR(BD[1], aB, ((b) * 2 + (kh)) * 16384 + 1 * 1024);                          \
  DSR(BD[2], aB, ((b) * 2 + (kh)) * 16384 + 2 * 1024);                          \
  DSR(BD[3], aB, ((b) * 2 + (kh)) * 16384 + 3 * 1024);                          \
} while (0)

// phase t: STG(t+3); VMCNT(8) retires slot t+1; LGKM(0) completes the reads
// of slot t (issued mid-cluster t-1); barA publishes slot t+1 AND fences the
// completed reads; cluster = 16 MFMA, 12 asm reads of slot t+1 (R12-proven
// mid-cluster placement), 16 MFMA. No trailing barrier.
#define PHASE(rb, rkh, AC, BC, AD, BD, STAGES, WAITS) do {                      \
  STAGES;                                                                       \
  WAITS;                                                                        \
  LGKM(0);                                                                      \
  __builtin_amdgcn_s_barrier();                                                 \
  __builtin_amdgcn_sched_barrier(0);                                            \
  __builtin_amdgcn_s_setprio(1);                                                \
  _Pragma("unroll")                                                             \
  for (int _m = 0; _m < 4; ++_m)                                                \
    _Pragma("unroll")                                                           \
    for (int _n = 0; _n < 4; ++_n)                                              \
      acc[_m][_n] = MF(AC[_m], BC[_n], acc[_m][_n]);                            \
  RD12(rb, rkh, AD, BD);                                                        \
  _Pragma("unroll")                                                             \
  for (int _m = 4; _m < 8; ++_m)                                                \
    _Pragma("unroll")                                                           \
    for (int _n = 0; _n < 4; ++_n)                                              \
      acc[_m][_n] = MF(AC[_m], BC[_n], acc[_m][_n]);                            \
  __builtin_amdgcn_s_setprio(0);                                                \
} while (0)

  // prologue: stage slots (0,0),(0,1),(1,0) = 12 vmem ops; retire slot (0,0)
  // (VMCNT(8)), publish, then asm-read its frags into P (completed by phase
  // 0's LGKM(0)).
  STG(SLOT_A(0, 0), Abf, offA0, 0);
  STG(SLOT_B(0, 0), Bbf, offB0, 0);
  STG(SLOT_A(0, 1), Abf, offA0, 32);
  STG(SLOT_B(0, 1), Bbf, offB0, 32);
  STG(SLOT_A(1, 0), Abf, offA0, 64);
  STG(SLOT_B(1, 0), Bbf, offB0, 64);
  VMCNT(8);
  __builtin_amdgcn_s_barrier();
  RD12(0, 0, aP, bP);

  // main loop: phases t=0..59. Consume slot t (P/Q regs), read-ahead t+1.
  for (int i = 0; i < 15; ++i) {
    int kb = i * 128;
    PHASE(0, 1, aP, bP, aQ, bQ, { STG(SLOT_A(1, 1), Abf, offA0, kb + 96);
                                  STG(SLOT_B(1, 1), Bbf, offB0, kb + 96); },
          VMCNT(8));
    PHASE(1, 0, aQ, bQ, aP, bP, { STG(SLOT_A(0, 0), Abf, offA0, kb + 128);
                                  STG(SLOT_B(0, 0), Bbf, offB0, kb + 128); },
          VMCNT(8));
    PHASE(1, 1, aP, bP, aQ, bQ, { STG(SLOT_A(0, 1), Abf, offA0, kb + 160);
                                  STG(SLOT_B(0, 1), Bbf, offB0, kb + 160); },
          VMCNT(8));
    PHASE(0, 0, aQ, bQ, aP, bP, { STG(SLOT_A(1, 0), Abf, offA0, kb + 192);
                                  STG(SLOT_B(1, 0), Bbf, offB0, kb + 192); },
          VMCNT(8));
  }
  // tail: t=60..62 (drain 8 -> 4 -> 0), then bare cluster at t=63.
  PHASE(0, 1, aP, bP, aQ, bQ, { STG(SLOT_A(1, 1), Abf, offA0, 2016);
                                STG(SLOT_B(1, 1), Bbf, offB0, 2016); },
        VMCNT(8));
  PHASE(1, 0, aQ, bQ, aP, bP, , VMCNT(4));
  PHASE(1, 1, aP, bP, aQ, bQ, , VMCNT(0));
  {
    LGKM(0);
    __builtin_amdgcn_sched_barrier(0);
#pragma unroll
    for (int m = 0; m < 8; ++m)
#pragma unroll
      for (int n = 0; n < 4; ++n)
        acc[m][n] = MF(aQ[m], bQ[n], acc[m][n]);
  }

  // epilogue: C/D layout (verified m89) col=lane&15, row=(lane>>4)*4+reg
  size_t crow = (size_t)(row0 + wr * 128 + fq * 4);
  int ccol = col0 + wc * 64 + fr;
#pragma unroll
  for (int m = 0; m < 8; ++m)
#pragma unroll
    for (int n = 0; n < 4; ++n) {
      float* cp = C + (crow + m * 16) * NDIM + ccol + n * 16;
#pragma unroll
      for (int e = 0; e < 4; ++e) cp[(size_t)e * NDIM] = acc[m][n][e];
    }
#undef PHASE
#undef RD12
#undef STG
#undef SLOT_A
#undef SLOT_B
}

// ---------------- fallback (fused conversion, 128^2 m97-structure) ----------

__global__ __launch_bounds__(256) void gemm_fused_fallback(
    const float* __restrict__ Afp,
    const float* __restrict__ Wfp,
    const int* __restrict__ Mk,
    float* __restrict__ C) {
  __shared__ unsigned short As[128 * 32];
  __shared__ unsigned short Bs[128 * 32];
  int bid = blockIdx.x;
  int nwg = (MDIM / 128) * (NDIM / 128);
  int wg = (bid & 7) * (nwg / 8) + (bid >> 3);
  int tm = wg >> 4, tn = wg & 15;
  int row0 = tm * 128, col0 = tn * 128;
  int t = threadIdx.x;
  int lane = t & 63, wv = t >> 6;
  int wr = wv >> 1, wc = wv & 1;
  int fr = lane & 15, fq = lane >> 4;
  f32x4 acc[4][4];
#pragma unroll
  for (int i = 0; i < 4; ++i)
#pragma unroll
    for (int j = 0; j < 4; ++j) acc[i][j] = f32x4{0.f, 0.f, 0.f, 0.f};
  for (int kt = 0; kt < KDIM; kt += 32) {
#pragma unroll
    for (int j = 0; j < 2; ++j) {
      int c = j * 256 + t;
      int r = c >> 2;
      int ko = (c & 3) * 8;
      const float* ga = Afp + (size_t)(row0 + r) * KDIM + kt + ko;
      float4 a0 = *reinterpret_cast<const float4*>(ga);
      float4 a1 = *reinterpret_cast<const float4*>(ga + 4);
      ushort8 va;
      va[0] = f2bf(a0.x); va[1] = f2bf(a0.y); va[2] = f2bf(a0.z); va[3] = f2bf(a0.w);
      va[4] = f2bf(a1.x); va[5] = f2bf(a1.y); va[6] = f2bf(a1.z); va[7] = f2bf(a1.w);
      *reinterpret_cast<ushort8*>(As + (size_t)c * 8) = va;
      const float* gw = Wfp + (size_t)(col0 + r) * KDIM + kt + ko;
      const int* gm = Mk + (size_t)(col0 + r) * KDIM + kt + ko;
      float4 w0 = *reinterpret_cast<const float4*>(gw);
      float4 w1 = *reinterpret_cast<const float4*>(gw + 4);
      int4 m0 = *reinterpret_cast<const int4*>(gm);
      int4 m1 = *reinterpret_cast<const int4*>(gm + 4);
      ushort8 vb;
      vb[0] = m0.x ? f2bf(w0.x) : (unsigned short)0;
      vb[1] = m0.y ? f2bf(w0.y) : (unsigned short)0;
      vb[2] = m0.z ? f2bf(w0.z) : (unsigned short)0;
      vb[3] = m0.w ? f2bf(w0.w) : (unsigned short)0;
      vb[4] = m1.x ? f2bf(w1.x) : (unsigned short)0;
      vb[5] = m1.y ? f2bf(w1.y) : (unsigned short)0;
      vb[6] = m1.z ? f2bf(w1.z) : (unsigned short)0;
      vb[7] = m1.w ? f2bf(w1.w) : (unsigned short)0;
      *reinterpret_cast<ushort8*>(Bs + (size_t)c * 8) = vb;
    }
    __syncthreads();
    bf16x8 af[4], bfr[4];
#pragma unroll
    for (int m2 = 0; m2 < 4; ++m2)
      af[m2] = *reinterpret_cast<const bf16x8*>(As + (wr * 64 + m2 * 16 + fr) * 32 + fq * 8);
#pragma unroll
    for (int n2 = 0; n2 < 4; ++n2)
      bfr[n2] = *reinterpret_cast<const bf16x8*>(Bs + (wc * 64 + n2 * 16 + fr) * 32 + fq * 8);
#pragma unroll
    for (int m2 = 0; m2 < 4; ++m2)
#pragma unroll
      for (int n2 = 0; n2 < 4; ++n2)
        acc[m2][n2] = MF(af[m2], bfr[n2], acc[m2][n2]);
    __syncthreads();
  }
#pragma unroll
  for (int m2 = 0; m2 < 4; ++m2)
#pragma unroll
    for (int n2 = 0; n2 < 4; ++n2) {
      size_t r0 = (size_t)(row0 + wr * 64 + m2 * 16 + fq * 4);
      size_t c0 = (size_t)(col0 + wc * 64 + n2 * 16 + fr);
#pragma unroll
      for (int i = 0; i < 4; ++i) C[(r0 + i) * NDIM + c0] = acc[m2][n2][i];
    }
}

// ---------------- launch ----------------

extern "C" void kernel_launch(void* const* d_in, const int* in_sizes, int n_in,
                              void* d_out, int out_size, void* d_ws, size_t ws_size,
                              hipStream_t stream) {
  const float* input  = (const float*)d_in[0];
  const float* weight = (const float*)d_in[1];
  const int*   mask   = (const int*)d_in[2];
  float* out = (float*)d_out;

  const size_t needA = (size_t)MDIM * KDIM * sizeof(unsigned short);
  const size_t needB = (size_t)NDIM * KDIM * sizeof(unsigned short);

  if (ws_size >= needA + needB) {
    unsigned short* Abf = (unsigned short*)d_ws;
    unsigned short* Bbf = (unsigned short*)((char*)d_ws + needA);
    convert_input_kernel<<<(MDIM * (size_t)KDIM / 8) / 256, 256, 0, stream>>>(input, Abf);
    convert_weight_kernel<<<(NDIM * (size_t)KDIM / 8) / 256, 256, 0, stream>>>(weight, mask, Bbf);
    gemm_1b<<<GRID_X, 512, 0, stream>>>(Abf, Bbf, out);
  } else {
    int nwg = (MDIM / 128) * (NDIM / 128);
    gemm_fused_fallback<<<nwg, 256, 0, stream>>>(input, weight, mask, out);
  }
}